// Round 8
// baseline (592.747 us; speedup 1.0000x reference)
//
#include <hip/hip_runtime.h>
#include <hip/hip_bf16.h>

typedef __bf16 bf16_t;
typedef bf16_t bf16x8 __attribute__((ext_vector_type(8)));
typedef float f32x4 __attribute__((ext_vector_type(4)));

// Pyramid layout: P[hg][16352][64] bf16, hg = b*16+h (64 head-groups).
// Row offsets per level l (rows per hg = 8192>>l):
//   {0, 8192, 12288, 14336, 15360, 15872, 16128, 16256, 16320}, total 16352.
#define PROWS 16352

// ---------------------------------------------------------------- helpers
__device__ __forceinline__ void gl_lds16(const bf16_t* g, bf16_t* l) {
  __builtin_amdgcn_global_load_lds(
      (const __attribute__((address_space(1))) void*)g,
      (__attribute__((address_space(3))) void*)l,
      16, 0, 0);
}

__device__ __forceinline__ void load8f(const bf16_t* p, float* f) {
  bf16x8 v = *(const bf16x8*)p;
#pragma unroll
  for (int e = 0; e < 8; ++e) f[e] = (float)v[e];
}
__device__ __forceinline__ void store8f(bf16_t* p, const float* f) {
  bf16x8 v;
#pragma unroll
  for (int e = 0; e < 8; ++e) v[e] = (bf16_t)f[e];
  *(bf16x8*)p = v;
}

// ---------------------------------------------------------------- fp32 -> bf16 (x)
__global__ __launch_bounds__(256) void cvt_f32_to_bf16(const float* __restrict__ in,
                                                       bf16_t* __restrict__ o) {
  size_t gid = (size_t)blockIdx.x * 256 + threadIdx.x;
  const float4* p = (const float4*)in + gid * 2;
  float4 a = p[0], b = p[1];
  bf16x8 v;
  v[0] = (bf16_t)a.x; v[1] = (bf16_t)a.y; v[2] = (bf16_t)a.z; v[3] = (bf16_t)a.w;
  v[4] = (bf16_t)b.x; v[5] = (bf16_t)b.y; v[6] = (bf16_t)b.z; v[7] = (bf16_t)b.w;
  *(bf16x8*)(o + gid * 8) = v;
}

// ---------------------------------------------------------------- weight transpose + cast: w[K][N] -> wT[N][K] bf16
__global__ __launch_bounds__(256) void transpose_to_bf16(const float* __restrict__ w,
                                                         bf16_t* __restrict__ wT,
                                                         int K, int N) {
  __shared__ float t[32][33];
  int bx = blockIdx.x, by = blockIdx.y;
  int tx = threadIdx.x & 31, ty = threadIdx.x >> 5;
#pragma unroll
  for (int r = ty; r < 32; r += 8)
    t[r][tx] = w[(size_t)(by * 32 + r) * N + bx * 32 + tx];
  __syncthreads();
#pragma unroll
  for (int r = ty; r < 32; r += 8)
    wT[(size_t)(bx * 32 + r) * K + by * 32 + tx] = (bf16_t)t[tx][r];
}

// ---------------------------------------------------------------- persistent 256x256 8-phase GEMM (T1+T2+T3+T4+T5)
// C[M][N] = A[M][K=1024] @ Bt[N][K=1024]^T.  8 waves, BK=64, dbuf LDS 128 KiB.
// Persistent: 256 blocks; tilesPerBlock tiles flattened into one pipeline.
// Tile/K coordinates maintained INCREMENTALLY (no div/mod in the loop);
// epilogue scatter uses per-fj hoisted base pointers (per-tile-constant hg/trow).
// EPI 0: scatter bf16 into pyramid P (qkv de-interleave, q scaled 0.125).
// EPI 1: fp32 C + bias.
template <int EPI>
__global__ __launch_bounds__(512, 2) void gemm256p(const bf16_t* __restrict__ A,
                                                   const bf16_t* __restrict__ Bt,
                                                   float* __restrict__ Cp,
                                                   const float* __restrict__ bias,
                                                   bf16_t* __restrict__ Pq,
                                                   bf16_t* __restrict__ Pk,
                                                   bf16_t* __restrict__ Pv,
                                                   int ldc, int nTilesN, int tilesPerBlock) {
  __shared__ __align__(16) bf16_t As[2 * 256 * 64];
  __shared__ __align__(16) bf16_t Bs[2 * 256 * 64];
  const int LD = 1024;
  const int tid = threadIdx.x;
  const int w = tid >> 6, lane = tid & 63;

  const int chunk = (blockIdx.x & 7) * 32 + (blockIdx.x >> 3);
  const int tile0 = chunk * tilesPerBlock;
  const int nSteps = tilesPerBlock * 16;

  const int wr = w >> 2, wc = w & 3;          // 2x4 wave grid; wave tile 128x64
  const int lr = lane & 15, lg = lane >> 4;
  const int sw = lr & 7;                      // T2 read-side XOR key
  f32x4 acc[8][4] = {};

  auto stageHalf = [&](const bf16_t* __restrict__ G, int rbase, int kt,
                       bf16_t* lbuf, int h) {
#pragma unroll
    for (int j = 0; j < 2; ++j) {
      int b = j * 8 + w;
      int r3 = lane >> 3;
      int k8 = (lane & 7) ^ r3;               // T2 pre-swizzled source slot
      gl_lds16(G + (size_t)(rbase + h * 128 + b * 8 + r3) * LD + kt + k8 * 8,
               lbuf + h * 8192 + b * 512);
    }
  };

  // epilogue coords (tile being accumulated) and stage coords (tile of step g+2)
  int ntEc = tile0 % nTilesN;
  int bmE = (tile0 / nTilesN) * 256, bnE = ntEc * 256;
  int nt2c = ntEc, bm2 = bmE, bn2 = bnE, kt2 = 128;   // g2=2 -> k-step 2 of tile0

  // prologue: steps 0 and 1 (both inside tile0)
  stageHalf(Bt, bnE, 0, Bs, 0); stageHalf(Bt, bnE, 0, Bs, 1);
  stageHalf(A, bmE, 0, As, 0);  stageHalf(A, bmE, 0, As, 1);
  stageHalf(Bt, bnE, 64, Bs + 16384, 0); stageHalf(Bt, bnE, 64, Bs + 16384, 1);
  stageHalf(A, bmE, 64, As + 16384, 0);  stageHalf(A, bmE, 64, As + 16384, 1);
  asm volatile("s_waitcnt vmcnt(8)" ::: "memory");   // step 0 landed
  __syncthreads();

  for (int g = 0; g < nSteps; ++g) {
    const int c = g & 1;
    bf16_t* Abuf = As + c * 16384;
    bf16_t* Bbuf = Bs + c * 16384;
    const bool pf = (g + 2) < nSteps;
    bf16x8 bfrag[4][2];

#pragma unroll
    for (int p = 0; p < 4; ++p) {
      bf16x8 afrag[2][2];
#pragma unroll
      for (int fi = 0; fi < 2; ++fi)
#pragma unroll
        for (int kk = 0; kk < 2; ++kk)
          afrag[fi][kk] = *(const bf16x8*)&Abuf[(wr * 128 + p * 32 + fi * 16 + lr) * 64 +
                                                (((kk * 4 + lg) ^ sw) * 8)];
      if (p == 0) {
#pragma unroll
        for (int fj = 0; fj < 4; ++fj)
#pragma unroll
          for (int kk = 0; kk < 2; ++kk)
            bfrag[fj][kk] = *(const bf16x8*)&Bbuf[(wc * 64 + fj * 16 + lr) * 64 +
                                                  (((kk * 4 + lg) ^ sw) * 8)];
      }
      if (pf) {
        if (p == 1) stageHalf(Bt, bn2, kt2, Bbuf, 0);
        if (p == 2) stageHalf(Bt, bn2, kt2, Bbuf, 1);
        if (p == 3) { stageHalf(A, bm2, kt2, Abuf, 0); stageHalf(A, bm2, kt2, Abuf, 1); }
      }
      __builtin_amdgcn_s_barrier();
      asm volatile("s_waitcnt lgkmcnt(0)" ::: "memory");
      __builtin_amdgcn_sched_barrier(0);
      __builtin_amdgcn_s_setprio(1);
#pragma unroll
      for (int kk = 0; kk < 2; ++kk)
#pragma unroll
        for (int fi = 0; fi < 2; ++fi)
#pragma unroll
          for (int fj = 0; fj < 4; ++fj)
            acc[p * 2 + fi][fj] = __builtin_amdgcn_mfma_f32_16x16x32_bf16(
                afrag[fi][kk], bfrag[fj][kk], acc[p * 2 + fi][fj], 0, 0, 0);
      __builtin_amdgcn_s_setprio(0);
      if (p == 3) {
        if (pf) asm volatile("s_waitcnt vmcnt(8)" ::: "memory");   // step g+1 landed
        else    asm volatile("s_waitcnt vmcnt(0)" ::: "memory");   // tail drain
      }
      __builtin_amdgcn_s_barrier();
    }

    // advance stage coords (incremental; no division)
    kt2 += 64;
    if (kt2 == 1024) {
      kt2 = 0; ++nt2c; bn2 += 256;
      if (nt2c == nTilesN) { nt2c = 0; bn2 = 0; bm2 += 256; }
    }

    if ((g & 15) == 15) {
      // ---- epilogue for the finished tile (overlaps next tile's staged loads)
      if (EPI == 1) {
        float bv[4];
#pragma unroll
        for (int fj = 0; fj < 4; ++fj) bv[fj] = bias[bnE + wc * 64 + fj * 16 + lr];
#pragma unroll
        for (int fi = 0; fi < 8; ++fi)
#pragma unroll
          for (int fj = 0; fj < 4; ++fj)
#pragma unroll
            for (int r = 0; r < 4; ++r) {
              int row = bmE + wr * 128 + fi * 16 + lg * 4 + r;
              int col = bnE + wc * 64 + fj * 16 + lr;
              Cp[(size_t)row * ldc + col] = acc[fi][fj][r] + bv[fj];
            }
      } else {
        // hoisted scatter: per-fj base pointer; 256-aligned tiles never straddle
        // the 8192-row boundary -> hg/trow base are per-tile constants.
        const int trow0 = (bmE & 8191) + wr * 128 + lg * 4;
        const int hgRow = (bmE >> 13) << 4;
#pragma unroll
        for (int fj = 0; fj < 4; ++fj) {
          int col = bnE + wc * 64 + fj * 16 + lr;
          int tns = col >> 10, col10 = col & 1023;
          int h = col10 >> 6, d = col10 & 63;
          bf16_t* Pt = (tns == 0) ? Pq : (tns == 1 ? Pk : Pv);
          bf16_t* bp = Pt + ((size_t)(hgRow + h) * PROWS + trow0) * 64 + d;
          float scl = (tns == 0) ? 0.125f : 1.f;
#pragma unroll
          for (int fi = 0; fi < 8; ++fi)
#pragma unroll
            for (int r = 0; r < 4; ++r)
              bp[(fi * 16 + r) * 64] = (bf16_t)(acc[fi][fj][r] * scl);
        }
      }
#pragma unroll
      for (int fi = 0; fi < 8; ++fi)
#pragma unroll
        for (int fj = 0; fj < 4; ++fj) acc[fi][fj] = (f32x4){};
      // advance epilogue coords
      ++ntEc; bnE += 256;
      if (ntEc == nTilesN) { ntEc = 0; bnE = 0; bmE += 256; }
    }
  }
}

// ---------------------------------------------------------------- fused pyramid coarsen, levels 1..8, one dispatch
__global__ __launch_bounds__(512) void coarsen_tree(bf16_t* __restrict__ Pq,
                                                    bf16_t* __restrict__ Pk,
                                                    bf16_t* __restrict__ Pv) {
  __shared__ float l6s[8][64];
  const int poffA[9] = {0, 8192, 12288, 14336, 15360, 15872, 16128, 16256, 16320};
  const int hg = blockIdx.x >> 4, win = blockIdx.x & 15;
  const int tid = threadIdx.x;
  const int d8 = tid & 7;
  const int tb = tid >> 3;
  const int wv = tid >> 6;
  const size_t base = (size_t)hg * PROWS;
  const int r0 = win * 512 + tb * 8;

#pragma unroll 1
  for (int tensor = 0; tensor < 3; ++tensor) {
    bf16_t* P = (tensor == 0) ? Pq : (tensor == 1 ? Pk : Pv);
    const float sc = (tensor == 2) ? 1.f : 0.5f;
    float v[8][8];
#pragma unroll
    for (int i = 0; i < 8; ++i) load8f(P + (base + r0 + i) * 64 + d8 * 8, v[i]);
    float a1[4][8];
#pragma unroll
    for (int i = 0; i < 4; ++i) {
#pragma unroll
      for (int e = 0; e < 8; ++e) a1[i][e] = sc * (v[2 * i][e] + v[2 * i + 1][e]);
      store8f(P + (base + poffA[1] + win * 256 + tb * 4 + i) * 64 + d8 * 8, a1[i]);
    }
    float a2[2][8];
#pragma unroll
    for (int i = 0; i < 2; ++i) {
#pragma unroll
      for (int e = 0; e < 8; ++e) a2[i][e] = sc * (a1[2 * i][e] + a1[2 * i + 1][e]);
      store8f(P + (base + poffA[2] + win * 128 + tb * 2 + i) * 64 + d8 * 8, a2[i]);
    }
    float a3[8];
#pragma unroll
    for (int e = 0; e < 8; ++e) a3[e] = sc * (a2[0][e] + a2[1][e]);
    store8f(P + (base + poffA[3] + win * 64 + tb) * 64 + d8 * 8, a3);
    float a4[8];
#pragma unroll
    for (int e = 0; e < 8; ++e) a4[e] = sc * (a3[e] + __shfl_xor(a3[e], 8, 64));
    if ((tb & 1) == 0) store8f(P + (base + poffA[4] + win * 32 + (tb >> 1)) * 64 + d8 * 8, a4);
    float a5[8];
#pragma unroll
    for (int e = 0; e < 8; ++e) a5[e] = sc * (a4[e] + __shfl_xor(a4[e], 16, 64));
    if ((tb & 3) == 0) store8f(P + (base + poffA[5] + win * 16 + (tb >> 2)) * 64 + d8 * 8, a5);
    float a6[8];
#pragma unroll
    for (int e = 0; e < 8; ++e) a6[e] = sc * (a5[e] + __shfl_xor(a5[e], 32, 64));
    if ((tb & 7) == 0) {
      bf16x8 o;
#pragma unroll
      for (int e = 0; e < 8; ++e) { l6s[wv][d8 * 8 + e] = a6[e]; o[e] = (bf16_t)a6[e]; }
      *(bf16x8*)(P + (base + poffA[6] + win * 8 + wv) * 64 + d8 * 8) = o;
    }
    __syncthreads();
    if (tid < 32) {
      int pr = tid >> 3;
      float a7[8];
#pragma unroll
      for (int e = 0; e < 8; ++e)
        a7[e] = sc * (l6s[2 * pr][d8 * 8 + e] + l6s[2 * pr + 1][d8 * 8 + e]);
      store8f(P + (base + poffA[7] + win * 4 + pr) * 64 + d8 * 8, a7);
      if (pr < 2) {
        float a8[8];
#pragma unroll
        for (int e = 0; e < 8; ++e)
          a8[e] = sc * (sc * (l6s[4 * pr][d8 * 8 + e] + l6s[4 * pr + 1][d8 * 8 + e]) +
                        sc * (l6s[4 * pr + 2][d8 * 8 + e] + l6s[4 * pr + 3][d8 * 8 + e]));
        store8f(P + (base + poffA[8] + win * 2 + pr) * 64 + d8 * 8, a8);
      }
    }
    __syncthreads();
  }
}

// ---------------------------------------------------------------- wave-level 16x16 MFMA block-attention core
// Returns via pointers: y written by caller-provided lambda-like dispatch.
// (Inlined manually in both kernels below.)

// levels 4..8: same as old attn_all, writes y in place + Asum (small grid)
__global__ __launch_bounds__(256) void attn_hi(bf16_t* __restrict__ Pq,
                                               const bf16_t* __restrict__ Pk,
                                               const bf16_t* __restrict__ Pv,
                                               float* __restrict__ Asum) {
  const int poffA[9] = {0, 8192, 12288, 14336, 15360, 15872, 16128, 16256, 16320};
  const int tid = threadIdx.x;
  const int wv = tid >> 6, lane = tid & 63;
  const int lr = lane & 15, lg = lane >> 4;

  int bid = blockIdx.x * 4 + wv;            // 3968 problems (levels 4-8)
  int l = 4, cnt = 2048;
  while (bid >= cnt) { bid -= cnt; cnt >>= 1; ++l; }
  const int lg2nblk = 9 - l;
  const int blk = bid & ((1 << lg2nblk) - 1);
  const int hg = bid >> lg2nblk;
  const int kvblk = blk ^ 1;
  const size_t qbase = (size_t)hg * PROWS + poffA[l] + blk * 16;
  const size_t kvbase = (size_t)hg * PROWS + poffA[l] + kvblk * 16;

  f32x4 s = {};
#pragma unroll
  for (int c = 0; c < 2; ++c) {
    bf16x8 ak = *(const bf16x8*)(Pk + (kvbase + lr) * 64 + c * 32 + lg * 8);
    bf16x8 bq = *(const bf16x8*)(Pq + (qbase + lr) * 64 + c * 32 + lg * 8);
    s = __builtin_amdgcn_mfma_f32_16x16x32_bf16(ak, bq, s, 0, 0, 0);
  }
  float mx = fmaxf(fmaxf(s[0], s[1]), fmaxf(s[2], s[3]));
  mx = fmaxf(mx, __shfl_xor(mx, 16, 64));
  mx = fmaxf(mx, __shfl_xor(mx, 32, 64));
  float a[4]; float asum = 0.f;
#pragma unroll
  for (int r = 0; r < 4; ++r) { a[r] = (float)(bf16_t)__expf(s[r] - mx); asum += a[r]; }
  asum += __shfl_xor(asum, 16, 64);
  asum += __shfl_xor(asum, 32, 64);
  if (lg == 0) Asum[qbase + lr] = asum;

  const int src0 = (2 * lg) * 16 + lr;
  const int src1 = (2 * lg + 1) * 16 + lr;
  bf16x8 pa;
#pragma unroll
  for (int r = 0; r < 4; ++r) {
    float c0 = __shfl(a[r], src0, 64);
    float c1 = __shfl(a[r], src1, 64);
    pa[r]     = (lg < 2) ? (bf16_t)c0 : (bf16_t)0.f;
    pa[r + 4] = (lg < 2) ? (bf16_t)c1 : (bf16_t)0.f;
  }
#pragma unroll
  for (int dt = 0; dt < 4; ++dt) {
    bf16x8 vf;
    if (lg < 2) {
#pragma unroll
      for (int e = 0; e < 8; ++e) vf[e] = Pv[(kvbase + lg * 8 + e) * 64 + dt * 16 + lr];
    } else {
#pragma unroll
      for (int e = 0; e < 8; ++e) vf[e] = (bf16_t)0.f;
    }
    f32x4 y = __builtin_amdgcn_mfma_f32_16x16x32_bf16(pa, vf, (f32x4){}, 0, 0, 0);
#pragma unroll
    for (int r = 0; r < 4; ++r)
      Pq[(qbase + 4 * lg + r) * 64 + dt * 16 + lr] = (bf16_t)y[r];
  }
}

// ---------------------------------------------------------------- fused attn L0-3 + combine
// Block = (hg, win of 256 L0 rows), 256 thr / 4 waves. Levels 0-3 are
// flip-partner-closed within the window. y+Asum -> LDS; combine adds tiny
// global L4-8 contributions and writes attnb directly.
__global__ __launch_bounds__(256) void attn_comb(const bf16_t* __restrict__ Pq,
                                                 const bf16_t* __restrict__ Pk,
                                                 const bf16_t* __restrict__ Pv,
                                                 const float* __restrict__ Ab,
                                                 bf16_t* __restrict__ attnb) {
  __shared__ __align__(16) bf16_t yl[480 * 72];   // rows: L0@0 L1@256 L2@384 L3@448, stride 72
  __shared__ float asl[480];
  const int poffA[9] = {0, 8192, 12288, 14336, 15360, 15872, 16128, 16256, 16320};
  const int loffA[4] = {0, 256, 384, 448};
  const int hg = blockIdx.x >> 5, win = blockIdx.x & 31;
  const int tid = threadIdx.x;
  const int wv = tid >> 6, lane = tid & 63;
  const int lr = lane & 15, lg = lane >> 4;

  auto do_attn = [&](int l, int blkL) {
    const int nb = 16 >> l;                      // blocks per window at level l
    const int blk = win * nb + blkL;
    const int kvblk = l ? (blk ^ 1) : blk;
    const size_t qbase = (size_t)hg * PROWS + poffA[l] + (size_t)blk * 16;
    const size_t kvbase = (size_t)hg * PROWS + poffA[l] + (size_t)kvblk * 16;
    const int lrow = loffA[l] + blkL * 16;

    f32x4 s = {};
#pragma unroll
    for (int c = 0; c < 2; ++c) {
      bf16x8 ak = *(const bf16x8*)(Pk + (kvbase + lr) * 64 + c * 32 + lg * 8);
      bf16x8 bq = *(const bf16x8*)(Pq + (qbase + lr) * 64 + c * 32 + lg * 8);
      s = __builtin_amdgcn_mfma_f32_16x16x32_bf16(ak, bq, s, 0, 0, 0);
    }
    float mx = fmaxf(fmaxf(s[0], s[1]), fmaxf(s[2], s[3]));
    mx = fmaxf(mx, __shfl_xor(mx, 16, 64));
    mx = fmaxf(mx, __shfl_xor(mx, 32, 64));
    float a[4]; float asum = 0.f;
#pragma unroll
    for (int r = 0; r < 4; ++r) { a[r] = (float)(bf16_t)__expf(s[r] - mx); asum += a[r]; }
    asum += __shfl_xor(asum, 16, 64);
    asum += __shfl_xor(asum, 32, 64);
    if (lg == 0) asl[lrow + lr] = asum;

    const int src0 = (2 * lg) * 16 + lr;
    const int src1 = (2 * lg + 1) * 16 + lr;
    bf16x8 pa;
#pragma unroll
    for (int r = 0; r < 4; ++r) {
      float c0 = __shfl(a[r], src0, 64);
      float c1 = __shfl(a[r], src1, 64);
      pa[r]     = (lg < 2) ? (bf16_t)c0 : (bf16_t)0.f;
      pa[r + 4] = (lg < 2) ? (bf16_t)c1 : (bf16_t)0.f;
    }
#pragma unroll
    for (int dt = 0; dt < 4; ++dt) {
      bf16x8 vf;
      if (lg < 2) {
#pragma unroll
        for (int e = 0; e < 8; ++e) vf[e] = Pv[(kvbase + lg * 8 + e) * 64 + dt * 16 + lr];
      } else {
#pragma unroll
        for (int e = 0; e < 8; ++e) vf[e] = (bf16_t)0.f;
      }
      f32x4 y = __builtin_amdgcn_mfma_f32_16x16x32_bf16(pa, vf, (f32x4){}, 0, 0, 0);
#pragma unroll
      for (int r = 0; r < 4; ++r)
        yl[(lrow + 4 * lg + r) * 72 + dt * 16 + lr] = (bf16_t)y[r];
    }
  };

  // task list: L0 x4, L1 x2, L2 x1, L3 (waves 0-1)
  do_attn(0, wv * 4 + 0); do_attn(0, wv * 4 + 1);
  do_attn(0, wv * 4 + 2); do_attn(0, wv * 4 + 3);
  do_attn(1, wv * 2 + 0); do_attn(1, wv * 2 + 1);
  do_attn(2, wv);
  if (wv < 2) do_attn(3, wv);
  __syncthreads();

  // combine: thread -> d8 = tid&7 (8 cols), rg = tid>>3 (8 rows each)
  const int d8 = tid & 7, rg = tid >> 3;
#pragma unroll
  for (int i = 0; i < 8; ++i) {
    const int r = rg * 8 + i;                 // local row in window
    const int t = win * 256 + r;              // level-0 row in hg
    float acc[8] = {};
    float asum = 0.f;
#pragma unroll
    for (int l = 0; l < 4; ++l) {
      const int row = loffA[l] + (r >> l);
      asum += asl[row];
      bf16x8 v = *(const bf16x8*)&yl[row * 72 + d8 * 8];
#pragma unroll
      for (int e = 0; e < 8; ++e) acc[e] += (float)v[e];
    }
#pragma unroll
    for (int l = 4; l < 9; ++l) {
      const size_t grow = (size_t)hg * PROWS + poffA[l] + (t >> l);
      asum += Ab[grow];
      bf16x8 v = *(const bf16x8*)(Pq + grow * 64 + d8 * 8);
#pragma unroll
      for (int e = 0; e < 8; ++e) acc[e] += (float)v[e];
    }
    const float inv = 1.f / (asum + 1e-8f);
    bf16x8 o;
#pragma unroll
    for (int e = 0; e < 8; ++e) o[e] = (bf16_t)(acc[e] * inv);
    *(bf16x8*)(attnb + ((size_t)(hg >> 4) * 8192 + t) * 1024 + (hg & 15) * 64 + d8 * 8) = o;
  }
}

// ---------------------------------------------------------------- launch
// Workspace (bytes), total 481,550,336 (~459.2 MiB):
//   Pq @ 0           127.75 MiB  [64][16352][64] bf16 (q; L4-8 y in place)
//   Pk @ 133955584   127.75 MiB
//   Pv @ 267911168   127.75 MiB
//   Ab @ 401866752   4 MiB       [64][16352] f32 Asum (L4-8 used)
//   woutT @ 406052864  2 MiB
//   x_bf @ 408150016  64 MiB     (dead after gemm1)
//   wqkvT @ 475258880 6 MiB      (dead after gemm1)
// Alias: attnb @ 408150016 over x_bf (dead after gemm1; Pk stays live for attn_comb).
extern "C" void kernel_launch(void* const* d_in, const int* in_sizes, int n_in,
                              void* d_out, int out_size, void* d_ws, size_t ws_size,
                              hipStream_t stream) {
  const float* x = (const float*)d_in[0];
  const float* wqkv = (const float*)d_in[1];
  const float* wout = (const float*)d_in[2];
  const float* bout = (const float*)d_in[3];
  float* out = (float*)d_out;
  (void)in_sizes; (void)n_in; (void)out_size; (void)ws_size;

  char* base = (char*)d_ws;
  bf16_t* Pq    = (bf16_t*)(base + 0);
  bf16_t* Pk    = (bf16_t*)(base + 133955584);
  bf16_t* Pv    = (bf16_t*)(base + 267911168);
  float*  Ab    = (float*)(base + 401866752);
  bf16_t* woutT = (bf16_t*)(base + 406052864);
  bf16_t* x_bf  = (bf16_t*)(base + 408150016);
  bf16_t* wqkvT = (bf16_t*)(base + 475258880);
  bf16_t* attnb = (bf16_t*)(base + 408150016);   // alias over dead x_bf

  cvt_f32_to_bf16<<<16384, 256, 0, stream>>>(x, x_bf);
  transpose_to_bf16<<<dim3(96, 32), 256, 0, stream>>>(wqkv, wqkvT, 1024, 3072);
  transpose_to_bf16<<<dim3(32, 32), 256, 0, stream>>>(wout, woutT, 1024, 1024);

  // qkv GEMM (persistent, 6 tiles/block) -> scatter into pyramid level 0
  gemm256p<0><<<256, 512, 0, stream>>>(x_bf, wqkvT, nullptr, nullptr, Pq, Pk, Pv,
                                       3072, 12, 6);

  coarsen_tree<<<1024, 512, 0, stream>>>(Pq, Pk, Pv);

  attn_hi<<<992, 256, 0, stream>>>(Pq, Pk, Pv, Ab);
  attn_comb<<<2048, 256, 0, stream>>>(Pq, Pk, Pv, Ab, attnb);

  // output GEMM (persistent, 2 tiles/block), fp32 + bias
  gemm256p<1><<<256, 512, 0, stream>>>(attnb, woutT, out, bout, nullptr, nullptr, nullptr,
                                       1024, 4, 2);
}

// Round 9
// 550.075 us; speedup vs baseline: 1.0776x; 1.0776x over previous
//
#include <hip/hip_runtime.h>
#include <hip/hip_bf16.h>

typedef __bf16 bf16_t;
typedef bf16_t bf16x8 __attribute__((ext_vector_type(8)));
typedef float f32x4 __attribute__((ext_vector_type(4)));

// Pyramid layout: P[hg][16352][64] bf16, hg = b*16+h (64 head-groups).
// Row offsets per level l: {0,8192,12288,14336,15360,15872,16128,16256,16320}.
// Levels 1-3 are NEVER materialized (derived on the fly in attn_comb);
// their row ranges are dead space.
#define PROWS 16352

// ---------------------------------------------------------------- helpers
__device__ __forceinline__ void gl_lds16(const bf16_t* g, bf16_t* l) {
  __builtin_amdgcn_global_load_lds(
      (const __attribute__((address_space(1))) void*)g,
      (__attribute__((address_space(3))) void*)l,
      16, 0, 0);
}

__device__ __forceinline__ void load8f(const bf16_t* p, float* f) {
  bf16x8 v = *(const bf16x8*)p;
#pragma unroll
  for (int e = 0; e < 8; ++e) f[e] = (float)v[e];
}
__device__ __forceinline__ void store8f(bf16_t* p, const float* f) {
  bf16x8 v;
#pragma unroll
  for (int e = 0; e < 8; ++e) v[e] = (bf16_t)f[e];
  *(bf16x8*)p = v;
}

// ---------------------------------------------------------------- fp32 -> bf16 (x)
__global__ __launch_bounds__(256) void cvt_f32_to_bf16(const float* __restrict__ in,
                                                       bf16_t* __restrict__ o) {
  size_t gid = (size_t)blockIdx.x * 256 + threadIdx.x;
  const float4* p = (const float4*)in + gid * 2;
  float4 a = p[0], b = p[1];
  bf16x8 v;
  v[0] = (bf16_t)a.x; v[1] = (bf16_t)a.y; v[2] = (bf16_t)a.z; v[3] = (bf16_t)a.w;
  v[4] = (bf16_t)b.x; v[5] = (bf16_t)b.y; v[6] = (bf16_t)b.z; v[7] = (bf16_t)b.w;
  *(bf16x8*)(o + gid * 8) = v;
}

// ---------------------------------------------------------------- weight transpose + cast: w[K][N] -> wT[N][K] bf16
__global__ __launch_bounds__(256) void transpose_to_bf16(const float* __restrict__ w,
                                                         bf16_t* __restrict__ wT,
                                                         int K, int N) {
  __shared__ float t[32][33];
  int bx = blockIdx.x, by = blockIdx.y;
  int tx = threadIdx.x & 31, ty = threadIdx.x >> 5;
#pragma unroll
  for (int r = ty; r < 32; r += 8)
    t[r][tx] = w[(size_t)(by * 32 + r) * N + bx * 32 + tx];
  __syncthreads();
#pragma unroll
  for (int r = ty; r < 32; r += 8)
    wT[(size_t)(bx * 32 + r) * K + by * 32 + tx] = (bf16_t)t[tx][r];
}

// ---------------------------------------------------------------- persistent 256x256 8-phase GEMM (T1+T2+T3+T4+T5)
// (unchanged from round 8 — the 248->261 delta is treated as variance)
template <int EPI>
__global__ __launch_bounds__(512, 2) void gemm256p(const bf16_t* __restrict__ A,
                                                   const bf16_t* __restrict__ Bt,
                                                   float* __restrict__ Cp,
                                                   const float* __restrict__ bias,
                                                   bf16_t* __restrict__ Pq,
                                                   bf16_t* __restrict__ Pk,
                                                   bf16_t* __restrict__ Pv,
                                                   int ldc, int nTilesN, int tilesPerBlock) {
  __shared__ __align__(16) bf16_t As[2 * 256 * 64];
  __shared__ __align__(16) bf16_t Bs[2 * 256 * 64];
  const int LD = 1024;
  const int tid = threadIdx.x;
  const int w = tid >> 6, lane = tid & 63;

  const int chunk = (blockIdx.x & 7) * 32 + (blockIdx.x >> 3);
  const int tile0 = chunk * tilesPerBlock;
  const int nSteps = tilesPerBlock * 16;

  const int wr = w >> 2, wc = w & 3;
  const int lr = lane & 15, lg = lane >> 4;
  const int sw = lr & 7;
  f32x4 acc[8][4] = {};

  auto stageHalf = [&](const bf16_t* __restrict__ G, int rbase, int kt,
                       bf16_t* lbuf, int h) {
#pragma unroll
    for (int j = 0; j < 2; ++j) {
      int b = j * 8 + w;
      int r3 = lane >> 3;
      int k8 = (lane & 7) ^ r3;
      gl_lds16(G + (size_t)(rbase + h * 128 + b * 8 + r3) * LD + kt + k8 * 8,
               lbuf + h * 8192 + b * 512);
    }
  };

  int ntEc = tile0 % nTilesN;
  int bmE = (tile0 / nTilesN) * 256, bnE = ntEc * 256;
  int nt2c = ntEc, bm2 = bmE, bn2 = bnE, kt2 = 128;

  stageHalf(Bt, bnE, 0, Bs, 0); stageHalf(Bt, bnE, 0, Bs, 1);
  stageHalf(A, bmE, 0, As, 0);  stageHalf(A, bmE, 0, As, 1);
  stageHalf(Bt, bnE, 64, Bs + 16384, 0); stageHalf(Bt, bnE, 64, Bs + 16384, 1);
  stageHalf(A, bmE, 64, As + 16384, 0);  stageHalf(A, bmE, 64, As + 16384, 1);
  asm volatile("s_waitcnt vmcnt(8)" ::: "memory");
  __syncthreads();

  for (int g = 0; g < nSteps; ++g) {
    const int c = g & 1;
    bf16_t* Abuf = As + c * 16384;
    bf16_t* Bbuf = Bs + c * 16384;
    const bool pf = (g + 2) < nSteps;
    bf16x8 bfrag[4][2];

#pragma unroll
    for (int p = 0; p < 4; ++p) {
      bf16x8 afrag[2][2];
#pragma unroll
      for (int fi = 0; fi < 2; ++fi)
#pragma unroll
        for (int kk = 0; kk < 2; ++kk)
          afrag[fi][kk] = *(const bf16x8*)&Abuf[(wr * 128 + p * 32 + fi * 16 + lr) * 64 +
                                                (((kk * 4 + lg) ^ sw) * 8)];
      if (p == 0) {
#pragma unroll
        for (int fj = 0; fj < 4; ++fj)
#pragma unroll
          for (int kk = 0; kk < 2; ++kk)
            bfrag[fj][kk] = *(const bf16x8*)&Bbuf[(wc * 64 + fj * 16 + lr) * 64 +
                                                  (((kk * 4 + lg) ^ sw) * 8)];
      }
      if (pf) {
        if (p == 1) stageHalf(Bt, bn2, kt2, Bbuf, 0);
        if (p == 2) stageHalf(Bt, bn2, kt2, Bbuf, 1);
        if (p == 3) { stageHalf(A, bm2, kt2, Abuf, 0); stageHalf(A, bm2, kt2, Abuf, 1); }
      }
      __builtin_amdgcn_s_barrier();
      asm volatile("s_waitcnt lgkmcnt(0)" ::: "memory");
      __builtin_amdgcn_sched_barrier(0);
      __builtin_amdgcn_s_setprio(1);
#pragma unroll
      for (int kk = 0; kk < 2; ++kk)
#pragma unroll
        for (int fi = 0; fi < 2; ++fi)
#pragma unroll
          for (int fj = 0; fj < 4; ++fj)
            acc[p * 2 + fi][fj] = __builtin_amdgcn_mfma_f32_16x16x32_bf16(
                afrag[fi][kk], bfrag[fj][kk], acc[p * 2 + fi][fj], 0, 0, 0);
      __builtin_amdgcn_s_setprio(0);
      if (p == 3) {
        if (pf) asm volatile("s_waitcnt vmcnt(8)" ::: "memory");
        else    asm volatile("s_waitcnt vmcnt(0)" ::: "memory");
      }
      __builtin_amdgcn_s_barrier();
    }

    kt2 += 64;
    if (kt2 == 1024) {
      kt2 = 0; ++nt2c; bn2 += 256;
      if (nt2c == nTilesN) { nt2c = 0; bn2 = 0; bm2 += 256; }
    }

    if ((g & 15) == 15) {
      if (EPI == 1) {
        float bv[4];
#pragma unroll
        for (int fj = 0; fj < 4; ++fj) bv[fj] = bias[bnE + wc * 64 + fj * 16 + lr];
#pragma unroll
        for (int fi = 0; fi < 8; ++fi)
#pragma unroll
          for (int fj = 0; fj < 4; ++fj)
#pragma unroll
            for (int r = 0; r < 4; ++r) {
              int row = bmE + wr * 128 + fi * 16 + lg * 4 + r;
              int col = bnE + wc * 64 + fj * 16 + lr;
              Cp[(size_t)row * ldc + col] = acc[fi][fj][r] + bv[fj];
            }
      } else {
        const int trow0 = (bmE & 8191) + wr * 128 + lg * 4;
        const int hgRow = (bmE >> 13) << 4;
#pragma unroll
        for (int fj = 0; fj < 4; ++fj) {
          int col = bnE + wc * 64 + fj * 16 + lr;
          int tns = col >> 10, col10 = col & 1023;
          int h = col10 >> 6, d = col10 & 63;
          bf16_t* Pt = (tns == 0) ? Pq : (tns == 1 ? Pk : Pv);
          bf16_t* bp = Pt + ((size_t)(hgRow + h) * PROWS + trow0) * 64 + d;
          float scl = (tns == 0) ? 0.125f : 1.f;
#pragma unroll
          for (int fi = 0; fi < 8; ++fi)
#pragma unroll
            for (int r = 0; r < 4; ++r)
              bp[(fi * 16 + r) * 64] = (bf16_t)(acc[fi][fj][r] * scl);
        }
      }
#pragma unroll
      for (int fi = 0; fi < 8; ++fi)
#pragma unroll
        for (int fj = 0; fj < 4; ++fj) acc[fi][fj] = (f32x4){};
      ++ntEc; bnE += 256;
      if (ntEc == nTilesN) { ntEc = 0; bnE = 0; bmE += 256; }
    }
  }
}

// ---------------------------------------------------------------- coarsen L0 -> levels 4..8 ONLY (L1-3 never materialized)
// Block = (hg, win of 256 L0 rows). tb = tid>>3 (32 row-groups of 8), d8 = tid&7.
// f32 sums: in-thread 8 rows -> shfl_xor(8/16/32) -> LDS hop for L7/L8.
// q,k: mean (scale 2^-l); v: sum.
__global__ __launch_bounds__(256) void coarsen_lite(bf16_t* __restrict__ Pq,
                                                    bf16_t* __restrict__ Pk,
                                                    bf16_t* __restrict__ Pv) {
  __shared__ float l6s[4][64];
  const int poffA[9] = {0, 8192, 12288, 14336, 15360, 15872, 16128, 16256, 16320};
  const int hg = blockIdx.x >> 5, win = blockIdx.x & 31;
  const int tid = threadIdx.x;
  const int d8 = tid & 7, tb = tid >> 3, wv = tid >> 6;
  const size_t base = (size_t)hg * PROWS;
  const int r0 = win * 256 + tb * 8;

#pragma unroll 1
  for (int tensor = 0; tensor < 3; ++tensor) {
    bf16_t* P = (tensor == 0) ? Pq : (tensor == 1 ? Pk : Pv);
    const bool isv = (tensor == 2);
    float s3[8] = {}, t[8], o[8];
#pragma unroll
    for (int i = 0; i < 8; ++i) {
      load8f(P + (base + r0 + i) * 64 + d8 * 8, t);
#pragma unroll
      for (int e = 0; e < 8; ++e) s3[e] += t[e];
    }
    float s4[8], s5[8], s6[8];
#pragma unroll
    for (int e = 0; e < 8; ++e) s4[e] = s3[e] + __shfl_xor(s3[e], 8, 64);
    if ((tb & 1) == 0) {
      float sc = isv ? 1.f : 0.0625f;
#pragma unroll
      for (int e = 0; e < 8; ++e) o[e] = s4[e] * sc;
      store8f(P + (base + poffA[4] + win * 16 + (tb >> 1)) * 64 + d8 * 8, o);
    }
#pragma unroll
    for (int e = 0; e < 8; ++e) s5[e] = s4[e] + __shfl_xor(s4[e], 16, 64);
    if ((tb & 3) == 0) {
      float sc = isv ? 1.f : 0.03125f;
#pragma unroll
      for (int e = 0; e < 8; ++e) o[e] = s5[e] * sc;
      store8f(P + (base + poffA[5] + win * 8 + (tb >> 2)) * 64 + d8 * 8, o);
    }
#pragma unroll
    for (int e = 0; e < 8; ++e) s6[e] = s5[e] + __shfl_xor(s5[e], 32, 64);
    if ((tb & 7) == 0) {
      float sc = isv ? 1.f : 0.015625f;
#pragma unroll
      for (int e = 0; e < 8; ++e) { o[e] = s6[e] * sc; l6s[wv][d8 * 8 + e] = s6[e]; }
      store8f(P + (base + poffA[6] + win * 4 + wv) * 64 + d8 * 8, o);
    }
    __syncthreads();
    if (tid < 16) {
      int pr = tid >> 3, dd = tid & 7;
      float sc7 = isv ? 1.f : 0.0078125f;
#pragma unroll
      for (int e = 0; e < 8; ++e)
        o[e] = (l6s[2 * pr][dd * 8 + e] + l6s[2 * pr + 1][dd * 8 + e]) * sc7;
      store8f(P + (base + poffA[7] + win * 2 + pr) * 64 + dd * 8, o);
    }
    if (tid < 8) {
      float sc8 = isv ? 1.f : 0.00390625f;
#pragma unroll
      for (int e = 0; e < 8; ++e)
        o[e] = (l6s[0][d8 * 8 + e] + l6s[1][d8 * 8 + e] +
                l6s[2][d8 * 8 + e] + l6s[3][d8 * 8 + e]) * sc8;
      store8f(P + (base + poffA[8] + win) * 64 + d8 * 8, o);
    }
    __syncthreads();
  }
}

// ---------------------------------------------------------------- levels 4..8 attention (reads pyramid, y in place + Asum)
__global__ __launch_bounds__(256) void attn_hi(bf16_t* __restrict__ Pq,
                                               const bf16_t* __restrict__ Pk,
                                               const bf16_t* __restrict__ Pv,
                                               float* __restrict__ Asum) {
  const int poffA[9] = {0, 8192, 12288, 14336, 15360, 15872, 16128, 16256, 16320};
  const int tid = threadIdx.x;
  const int wv = tid >> 6, lane = tid & 63;
  const int lr = lane & 15, lg = lane >> 4;

  int bid = blockIdx.x * 4 + wv;            // 3968 problems (levels 4-8)
  int l = 4, cnt = 2048;
  while (bid >= cnt) { bid -= cnt; cnt >>= 1; ++l; }
  const int lg2nblk = 9 - l;
  const int blk = bid & ((1 << lg2nblk) - 1);
  const int hg = bid >> lg2nblk;
  const int kvblk = blk ^ 1;
  const size_t qbase = (size_t)hg * PROWS + poffA[l] + blk * 16;
  const size_t kvbase = (size_t)hg * PROWS + poffA[l] + kvblk * 16;

  f32x4 s = {};
#pragma unroll
  for (int c = 0; c < 2; ++c) {
    bf16x8 ak = *(const bf16x8*)(Pk + (kvbase + lr) * 64 + c * 32 + lg * 8);
    bf16x8 bq = *(const bf16x8*)(Pq + (qbase + lr) * 64 + c * 32 + lg * 8);
    s = __builtin_amdgcn_mfma_f32_16x16x32_bf16(ak, bq, s, 0, 0, 0);
  }
  float mx = fmaxf(fmaxf(s[0], s[1]), fmaxf(s[2], s[3]));
  mx = fmaxf(mx, __shfl_xor(mx, 16, 64));
  mx = fmaxf(mx, __shfl_xor(mx, 32, 64));
  float a[4]; float asum = 0.f;
#pragma unroll
  for (int r = 0; r < 4; ++r) { a[r] = (float)(bf16_t)__expf(s[r] - mx); asum += a[r]; }
  asum += __shfl_xor(asum, 16, 64);
  asum += __shfl_xor(asum, 32, 64);
  if (lg == 0) Asum[qbase + lr] = asum;

  const int src0 = (2 * lg) * 16 + lr;
  const int src1 = (2 * lg + 1) * 16 + lr;
  bf16x8 pa;
#pragma unroll
  for (int r = 0; r < 4; ++r) {
    float c0 = __shfl(a[r], src0, 64);
    float c1 = __shfl(a[r], src1, 64);
    pa[r]     = (lg < 2) ? (bf16_t)c0 : (bf16_t)0.f;
    pa[r + 4] = (lg < 2) ? (bf16_t)c1 : (bf16_t)0.f;
  }
#pragma unroll
  for (int dt = 0; dt < 4; ++dt) {
    bf16x8 vf;
    if (lg < 2) {
#pragma unroll
      for (int e = 0; e < 8; ++e) vf[e] = Pv[(kvbase + lg * 8 + e) * 64 + dt * 16 + lr];
    } else {
#pragma unroll
      for (int e = 0; e < 8; ++e) vf[e] = (bf16_t)0.f;
    }
    f32x4 y = __builtin_amdgcn_mfma_f32_16x16x32_bf16(pa, vf, (f32x4){}, 0, 0, 0);
#pragma unroll
    for (int r = 0; r < 4; ++r)
      Pq[(qbase + 4 * lg + r) * 64 + dt * 16 + lr] = (bf16_t)y[r];
  }
}

// ---------------------------------------------------------------- fused attn L0-3 + combine, L1-3 derived on the fly
// Block = (hg, win of 256 L0 rows). Q/K frags for l>=1: average 2^l L0 rows
// (cache-hot window, f32 chain -> one bf16 rounding). PV for l>=1: expanded-P
// identity  sum_j p[j] V_l[j] = sum_r p[r>>l] V0[r]  as 2^(l-1) K=32 MFMAs
// against raw V0 rows (no zero-pad). y+Asum -> LDS; combine adds L4-8 global.
__global__ __launch_bounds__(256) void attn_comb(const bf16_t* __restrict__ Pq,
                                                 const bf16_t* __restrict__ Pk,
                                                 const bf16_t* __restrict__ Pv,
                                                 const float* __restrict__ Ab,
                                                 bf16_t* __restrict__ attnb) {
  __shared__ __align__(16) bf16_t yl[480 * 72];   // L0@0 L1@256 L2@384 L3@448, stride 72
  __shared__ float asl[480];
  const int poffA[9] = {0, 8192, 12288, 14336, 15360, 15872, 16128, 16256, 16320};
  const int loffA[4] = {0, 256, 384, 448};
  const int hg = blockIdx.x >> 5, win = blockIdx.x & 31;
  const int tid = threadIdx.x;
  const int wv = tid >> 6, lane = tid & 63;
  const int lr = lane & 15, lg = lane >> 4;
  const size_t hb = (size_t)hg * PROWS;           // L0 base row of this hg

  auto do_attn = [&](int l, int blkL) {
    const int blk = win * (16 >> l) + blkL;       // level-l block index in hg
    const int kvblk = l ? (blk ^ 1) : blk;
    const int lrow = loffA[l] + blkL * 16;
    const int q0 = (blk * 16 + lr) << l;          // L0 base row for q row lr
    const int k0 = (kvblk * 16 + lr) << l;        // L0 base row for k row lr
    const int kv0 = (kvblk * 16) << l;            // L0 base row of kv block
    const float scl = 1.f / (float)(1 << l);

    // ---- QK^T: derive K_l/Q_l row-frags by averaging 2^l L0 rows
    f32x4 s = {};
#pragma unroll
    for (int c = 0; c < 2; ++c) {
      float fk[8] = {}, fq[8] = {}, t[8];
      for (int m = 0; m < (1 << l); ++m) {
        load8f(Pk + (hb + k0 + m) * 64 + c * 32 + lg * 8, t);
#pragma unroll
        for (int e = 0; e < 8; ++e) fk[e] += t[e];
        load8f(Pq + (hb + q0 + m) * 64 + c * 32 + lg * 8, t);
#pragma unroll
        for (int e = 0; e < 8; ++e) fq[e] += t[e];
      }
      bf16x8 ak, bq;
#pragma unroll
      for (int e = 0; e < 8; ++e) {
        ak[e] = (bf16_t)(fk[e] * scl);
        bq[e] = (bf16_t)(fq[e] * scl);
      }
      s = __builtin_amdgcn_mfma_f32_16x16x32_bf16(ak, bq, s, 0, 0, 0);
    }

    // ---- softmax over j (S^T layout: lane holds S[lr][4lg+r])
    float mx = fmaxf(fmaxf(s[0], s[1]), fmaxf(s[2], s[3]));
    mx = fmaxf(mx, __shfl_xor(mx, 16, 64));
    mx = fmaxf(mx, __shfl_xor(mx, 32, 64));
    float a[4]; float asum = 0.f;
#pragma unroll
    for (int r = 0; r < 4; ++r) { a[r] = (float)(bf16_t)__expf(s[r] - mx); asum += a[r]; }
    asum += __shfl_xor(asum, 16, 64);
    asum += __shfl_xor(asum, 32, 64);
    if (lg == 0) asl[lrow + lr] = asum;

    if (l == 0) {
      // K=16 zero-padded path (lanes lg>=2 zero)
      const int src0 = (2 * lg) * 16 + lr;
      const int src1 = (2 * lg + 1) * 16 + lr;
      bf16x8 pa;
#pragma unroll
      for (int r = 0; r < 4; ++r) {
        float c0 = __shfl(a[r], src0, 64);
        float c1 = __shfl(a[r], src1, 64);
        pa[r]     = (lg < 2) ? (bf16_t)c0 : (bf16_t)0.f;
        pa[r + 4] = (lg < 2) ? (bf16_t)c1 : (bf16_t)0.f;
      }
#pragma unroll
      for (int dt = 0; dt < 4; ++dt) {
        bf16x8 vf;
        if (lg < 2) {
#pragma unroll
          for (int e = 0; e < 8; ++e) vf[e] = Pv[(hb + kv0 + lg * 8 + e) * 64 + dt * 16 + lr];
        } else {
#pragma unroll
          for (int e = 0; e < 8; ++e) vf[e] = (bf16_t)0.f;
        }
        f32x4 y = __builtin_amdgcn_mfma_f32_16x16x32_bf16(pa, vf, (f32x4){}, 0, 0, 0);
#pragma unroll
        for (int r = 0; r < 4; ++r)
          yl[(lrow + 4 * lg + r) * 72 + dt * 16 + lr] = (bf16_t)y[r];
      }
    } else {
      // expanded-P: y[i][d] = sum_r p_i[r>>l] V0[kv0+r][d], chunks of K=32
      const int nch = 1 << (l - 1);
      bf16x8 pa[4];                         // nch <= 4
      for (int ch = 0; ch < nch; ++ch) {
        if (l == 1) {
#pragma unroll
          for (int e = 0; e < 8; ++e) pa[ch][e] = (bf16_t)a[e >> 1];
        } else if (l == 2) {
          int src = (2 * ch + (lg >> 1)) * 16 + lr;
          float t0 = __shfl(a[0], src, 64), t1 = __shfl(a[1], src, 64);
          float t2 = __shfl(a[2], src, 64), t3 = __shfl(a[3], src, 64);
          float vlo = (lg & 1) ? t2 : t0;   // component (2lg)&3
          float vhi = (lg & 1) ? t3 : t1;   // component (2lg+1)&3
#pragma unroll
          for (int e = 0; e < 4; ++e) { pa[ch][e] = (bf16_t)vlo; pa[ch][e + 4] = (bf16_t)vhi; }
        } else {                            // l == 3
          int src = ch * 16 + lr;
          float t0 = __shfl(a[0], src, 64), t1 = __shfl(a[1], src, 64);
          float t2 = __shfl(a[2], src, 64), t3 = __shfl(a[3], src, 64);
          float v01 = (lg & 1) ? t1 : t0;
          float v23 = (lg & 1) ? t3 : t2;
          float vv = (lg & 2) ? v23 : v01;  // component lg
#pragma unroll
          for (int e = 0; e < 8; ++e) pa[ch][e] = (bf16_t)vv;
        }
      }
#pragma unroll
      for (int dt = 0; dt < 4; ++dt) {
        f32x4 y = {};
        for (int ch = 0; ch < nch; ++ch) {
          bf16x8 vf;
#pragma unroll
          for (int e = 0; e < 8; ++e)
            vf[e] = Pv[(hb + kv0 + ch * 32 + lg * 8 + e) * 64 + dt * 16 + lr];
          y = __builtin_amdgcn_mfma_f32_16x16x32_bf16(pa[ch], vf, y, 0, 0, 0);
        }
#pragma unroll
        for (int r = 0; r < 4; ++r)
          yl[(lrow + 4 * lg + r) * 72 + dt * 16 + lr] = (bf16_t)y[r];
      }
    }
  };

  // task list per wave: L0 x4, L1 x2, L2 x1, L3 (waves 0-1)
  do_attn(0, wv * 4 + 0); do_attn(0, wv * 4 + 1);
  do_attn(0, wv * 4 + 2); do_attn(0, wv * 4 + 3);
  do_attn(1, wv * 2 + 0); do_attn(1, wv * 2 + 1);
  do_attn(2, wv);
  if (wv < 2) do_attn(3, wv);
  __syncthreads();

  // combine: thread -> d8 = tid&7, rg = tid>>3 (8 rows each)
  const int d8 = tid & 7, rg = tid >> 3;
#pragma unroll
  for (int i = 0; i < 8; ++i) {
    const int r = rg * 8 + i;
    const int t = win * 256 + r;
    float acc[8] = {};
    float asum = 0.f;
#pragma unroll
    for (int l = 0; l < 4; ++l) {
      const int row = loffA[l] + (r >> l);
      asum += asl[row];
      bf16x8 v = *(const bf16x8*)&yl[row * 72 + d8 * 8];
#pragma unroll
      for (int e = 0; e < 8; ++e) acc[e] += (float)v[e];
    }
#pragma unroll
    for (int l = 4; l < 9; ++l) {
      const size_t grow = hb + poffA[l] + (t >> l);
      asum += Ab[grow];
      bf16x8 v = *(const bf16x8*)(Pq + grow * 64 + d8 * 8);
#pragma unroll
      for (int e = 0; e < 8; ++e) acc[e] += (float)v[e];
    }
    const float inv = 1.f / (asum + 1e-8f);
    bf16x8 o;
#pragma unroll
    for (int e = 0; e < 8; ++e) o[e] = (bf16_t)(acc[e] * inv);
    *(bf16x8*)(attnb + ((size_t)(hg >> 4) * 8192 + t) * 1024 + (hg & 15) * 64 + d8 * 8) = o;
  }
}

// ---------------------------------------------------------------- launch
// Workspace (bytes), total 481,550,336 (~459.2 MiB):
//   Pq @ 0           127.75 MiB  [64][16352][64] bf16 (q; L4-8 y in place)
//   Pk @ 133955584   127.75 MiB
//   Pv @ 267911168   127.75 MiB
//   Ab @ 401866752   4 MiB       [64][16352] f32 Asum (L4-8 used)
//   woutT @ 406052864  2 MiB
//   x_bf @ 408150016  64 MiB     (dead after gemm1)
//   wqkvT @ 475258880 6 MiB      (dead after gemm1)
// Alias: attnb @ 408150016 over x_bf (dead after gemm1).
extern "C" void kernel_launch(void* const* d_in, const int* in_sizes, int n_in,
                              void* d_out, int out_size, void* d_ws, size_t ws_size,
                              hipStream_t stream) {
  const float* x = (const float*)d_in[0];
  const float* wqkv = (const float*)d_in[1];
  const float* wout = (const float*)d_in[2];
  const float* bout = (const float*)d_in[3];
  float* out = (float*)d_out;
  (void)in_sizes; (void)n_in; (void)out_size; (void)ws_size;

  char* base = (char*)d_ws;
  bf16_t* Pq    = (bf16_t*)(base + 0);
  bf16_t* Pk    = (bf16_t*)(base + 133955584);
  bf16_t* Pv    = (bf16_t*)(base + 267911168);
  float*  Ab    = (float*)(base + 401866752);
  bf16_t* woutT = (bf16_t*)(base + 406052864);
  bf16_t* x_bf  = (bf16_t*)(base + 408150016);
  bf16_t* wqkvT = (bf16_t*)(base + 475258880);
  bf16_t* attnb = (bf16_t*)(base + 408150016);   // alias over dead x_bf

  cvt_f32_to_bf16<<<16384, 256, 0, stream>>>(x, x_bf);
  transpose_to_bf16<<<dim3(96, 32), 256, 0, stream>>>(wqkv, wqkvT, 1024, 3072);
  transpose_to_bf16<<<dim3(32, 32), 256, 0, stream>>>(wout, woutT, 1024, 1024);

  // qkv GEMM (persistent, 6 tiles/block) -> scatter into pyramid level 0
  gemm256p<0><<<256, 512, 0, stream>>>(x_bf, wqkvT, nullptr, nullptr, Pq, Pk, Pv,
                                       3072, 12, 6);

  coarsen_lite<<<2048, 256, 0, stream>>>(Pq, Pk, Pv);

  attn_hi<<<992, 256, 0, stream>>>(Pq, Pk, Pv, Ab);
  attn_comb<<<2048, 256, 0, stream>>>(Pq, Pk, Pv, Ab, attnb);

  // output GEMM (persistent, 2 tiles/block), fp32 + bias
  gemm256p<1><<<256, 512, 0, stream>>>(attnb, woutT, out, bout, nullptr, nullptr, nullptr,
                                       1024, 4, 2);
}